// Round 3
// baseline (848.372 us; speedup 1.0000x reference)
//
#include <hip/hip_runtime.h>
#include <hip/hip_bf16.h>

#define N_NODES 100000
#define N_EDGES 1600000
#define BN_EPS 1e-5f

__device__ __forceinline__ float sigf(float x) { return 1.0f / (1.0f + expf(-x)); }

// ---- utility fills ---------------------------------------------------------
__global__ void k_zero_f(float* __restrict__ p, int n) {
    int i = blockIdx.x * 256 + threadIdx.x;
    if (i < n) p[i] = 0.f;
}
__global__ void k_marker(float* __restrict__ p, int n, float v) {
    int i = blockIdx.x * 256 + threadIdx.x;
    if (i < n) p[i] = v;
}

// ---- deg[dst] += ew --------------------------------------------------------
__global__ void k_deg(const int* __restrict__ ei, const float* __restrict__ ew,
                      float* __restrict__ deg) {
    int e = blockIdx.x * 256 + threadIdx.x;
    if (e < N_EDGES) atomicAdd(&deg[ei[N_EDGES + e]], ew[e]);
}

// ---- column sums of x (for skip_avg) ---------------------------------------
__global__ void k_xmean(const float* __restrict__ x, float* __restrict__ xsum) {
    __shared__ float s[256];
    int f = threadIdx.x & 31, rg = threadIdx.x >> 5;
    float acc = 0.f;
    for (int n = blockIdx.x * 8 + rg; n < N_NODES; n += gridDim.x * 8)
        acc += x[n * 32 + f];
    s[threadIdx.x] = acc; __syncthreads();
    for (int st = 128; st >= 32; st >>= 1) {
        if (threadIdx.x < st) s[threadIdx.x] += s[threadIdx.x + st];
        __syncthreads();
    }
    if (threadIdx.x < 32) atomicAdd(&xsum[threadIdx.x], s[threadIdx.x]);
}

// ---- A = x @ W1 ------------------------------------------------------------
__global__ void k_xw1(const float* __restrict__ x, const float* __restrict__ w,
                      float* __restrict__ A) {
    __shared__ float Ws[32 * 33];
    __shared__ float xs[256];
    for (int i = threadIdx.x; i < 1024; i += 256)
        Ws[(i >> 5) * 33 + (i & 31)] = w[i];
    long base = (long)blockIdx.x * 256;
    xs[threadIdx.x] = x[base + threadIdx.x];
    __syncthreads();
    int r = threadIdx.x >> 5, h = threadIdx.x & 31;
    float acc = 0.f;
#pragma unroll
    for (int f = 0; f < 32; f++) acc += xs[r * 32 + f] * Ws[f * 33 + h];
    A[base + threadIdx.x] = acc;
}

// ---- B[dst] += A[src] * norm  (32 lanes per edge, norm inline) -------------
__global__ void k_agg(const int* __restrict__ ei, const float* __restrict__ ew,
                      const float* __restrict__ deg, const float* __restrict__ A,
                      float* __restrict__ B) {
    long gid = (long)blockIdx.x * 256 + threadIdx.x;
    long e = gid >> 5; int f = (int)(gid & 31);
    if (e < N_EDGES) {
        int s = ei[e], d = ei[N_EDGES + e];
        float nm = ew[e] * rsqrtf((deg[s] + 1.0f) * (deg[d] + 1.0f));
        atomicAdd(&B[(long)d * 32 + f], A[(long)s * 32 + f] * nm);
    }
}

// ---- r = relu(B + A/deg + bias) in-place; accumulate BN sum/sumsq ----------
__global__ void k_post(const float* __restrict__ A, const float* __restrict__ deg,
                       const float* __restrict__ bias, float* __restrict__ B,
                       float* __restrict__ sum, float* __restrict__ sq) {
    __shared__ float s1[256], s2[256];
    int f = threadIdx.x & 31, rg = threadIdx.x >> 5;
    float bv = bias[f];
    float a1 = 0.f, a2 = 0.f;
    for (int n = blockIdx.x * 8 + rg; n < N_NODES; n += gridDim.x * 8) {
        long i = (long)n * 32 + f;
        float v = B[i] + A[i] / (deg[n] + 1.0f) + bv;
        v = fmaxf(v, 0.f);
        B[i] = v;
        a1 += v; a2 += v * v;
    }
    s1[threadIdx.x] = a1; s2[threadIdx.x] = a2; __syncthreads();
    for (int st = 128; st >= 32; st >>= 1) {
        if (threadIdx.x < st) {
            s1[threadIdx.x] += s1[threadIdx.x + st];
            s2[threadIdx.x] += s2[threadIdx.x + st];
        }
        __syncthreads();
    }
    if (threadIdx.x < 32) { atomicAdd(&sum[f], s1[f]); atomicAdd(&sq[f], s2[f]); }
}

// ---- BN1 finalize ----------------------------------------------------------
__global__ void k_fin1(const float* __restrict__ sum, const float* __restrict__ sq,
                       const float* __restrict__ g, const float* __restrict__ be,
                       float* __restrict__ scale, float* __restrict__ shift) {
    int t = threadIdx.x;
    if (t < 32) {
        float mu = sum[t] / (float)N_NODES;
        float var = sq[t] / (float)N_NODES - mu * mu;
        float rs = rsqrtf(var + BN_EPS) * g[t];
        scale[t] = rs;
        shift[t] = be[t] - mu * rs;
    }
}

// ---- H = affine(B); A = H @ W2 ---------------------------------------------
__global__ void k_aff_xw(const float* __restrict__ B, const float* __restrict__ scale,
                         const float* __restrict__ shift, const float* __restrict__ w,
                         float* __restrict__ H, float* __restrict__ A) {
    __shared__ float Ws[32 * 33];
    __shared__ float hs[256];
    for (int i = threadIdx.x; i < 1024; i += 256)
        Ws[(i >> 5) * 33 + (i & 31)] = w[i];
    long base = (long)blockIdx.x * 256;
    int f = threadIdx.x & 31;
    float h = B[base + threadIdx.x] * scale[f] + shift[f];
    H[base + threadIdx.x] = h;
    hs[threadIdx.x] = h;
    __syncthreads();
    int r = threadIdx.x >> 5, hc = threadIdx.x & 31;
    float acc = 0.f;
#pragma unroll
    for (int k = 0; k < 32; k++) acc += hs[r * 32 + k] * Ws[k * 33 + hc];
    A[base + threadIdx.x] = acc;
}

// ---- BN2 finalize + fc1 const + combined LSTM biases -----------------------
__global__ void k_fin2(const float* __restrict__ sum, const float* __restrict__ sq,
                       const float* __restrict__ g, const float* __restrict__ be,
                       const float* __restrict__ xsum, const float* __restrict__ fw1,
                       const float* __restrict__ fb1,
                       const float* __restrict__ bih1, const float* __restrict__ bhh1,
                       const float* __restrict__ bih2, const float* __restrict__ bhh2,
                       float* __restrict__ scale, float* __restrict__ shift,
                       float* __restrict__ fc1c, float* __restrict__ lb1,
                       float* __restrict__ lb2) {
    int t = threadIdx.x;
    if (t < 32) {
        float mu = sum[t] / (float)N_NODES;
        float var = sq[t] / (float)N_NODES - mu * mu;
        float rs = rsqrtf(var + BN_EPS) * g[t];
        scale[t] = rs;
        shift[t] = be[t] - mu * rs;
        float c = fb1[t];
        for (int f = 0; f < 32; f++)
            c += (xsum[f] / (float)N_NODES) * fw1[t * 96 + 64 + f];
        fc1c[t] = c;
    }
    if (t < 128) {
        lb1[t] = bih1[t] + bhh1[t];
        lb2[t] = bih2[t] + bhh2[t];
    }
}

// ---- per-node LSTM1 -> LSTM2 -> fc1 -> fc2 (32 lanes per node) -------------
__global__ __launch_bounds__(256) void k_final(
    const float* __restrict__ H, const float* __restrict__ B,
    const float* __restrict__ scale2, const float* __restrict__ shift2,
    const float* __restrict__ wih1, const float* __restrict__ wih2,
    const float* __restrict__ fw1, const float* __restrict__ fw2,
    const float* __restrict__ fb2,
    const float* __restrict__ fc1c, const float* __restrict__ lb1,
    const float* __restrict__ lb2, float* __restrict__ out) {
    __shared__ float W1s[64 * 96];   // [k][c]: c<32 gate-i; 32..63 -> g; 64..95 -> o
    __shared__ float W2s[32 * 96];
    __shared__ float F1s[64 * 32];   // [k][j] = fw1[j][k]
    __shared__ float lb1s[128], lb2s[128], fc1s[32], fw2s[32], sc2[32], sh2[32];
    int tid = threadIdx.x;
    for (int i = tid; i < 64 * 96; i += 256) {
        int k = i / 96, c = i % 96;
        int row = (c < 32) ? c : c + 32;          // skip dead f rows 32..63
        W1s[i] = wih1[row * 64 + k];
    }
    for (int i = tid; i < 32 * 96; i += 256) {
        int k = i / 96, c = i % 96;
        int row = (c < 32) ? c : c + 32;
        W2s[i] = wih2[row * 32 + k];
    }
    for (int i = tid; i < 64 * 32; i += 256) {
        int k = i >> 5, j = i & 31;
        F1s[i] = fw1[j * 96 + k];
    }
    if (tid < 128) { lb1s[tid] = lb1[tid]; lb2s[tid] = lb2[tid]; }
    if (tid < 32) {
        fc1s[tid] = fc1c[tid]; fw2s[tid] = fw2[tid];
        sc2[tid] = scale2[tid]; sh2[tid] = shift2[tid];
    }
    __syncthreads();
    float fb2v = fb2[0];
    int j = tid & 31;
    int sub = tid >> 5;
    for (long base = (long)blockIdx.x * 8; base < N_NODES; base += (long)gridDim.x * 8) {
        long n = base + sub;
        float hj  = H[n * 32 + j];
        float h2j = B[n * 32 + j] * sc2[j] + sh2[j];
        float ai = lb1s[j], ag = lb1s[64 + j], ao = lb1s[96 + j];
#pragma unroll
        for (int k = 0; k < 32; k++) {
            float hv  = __shfl(hj,  k, 32);
            float h2v = __shfl(h2j, k, 32);
            const float* r1 = &W1s[k * 96];
            const float* r2 = &W1s[(k + 32) * 96];
            ai += r1[j] * hv + r2[j] * h2v;
            ag += r1[32 + j] * hv + r2[32 + j] * h2v;
            ao += r1[64 + j] * hv + r2[64 + j] * h2v;
        }
        float c1  = sigf(ai) * tanhf(ag);
        float hn1 = sigf(ao) * tanhf(c1);
        float bi = lb2s[j], bg = lb2s[64 + j], bo = lb2s[96 + j];
#pragma unroll
        for (int k = 0; k < 32; k++) {
            float hv = __shfl(hn1, k, 32);
            const float* r = &W2s[k * 96];
            bi += r[j] * hv; bg += r[32 + j] * hv; bo += r[64 + j] * hv;
        }
        float c2  = sigf(bi) * tanhf(bg);
        float hn2 = sigf(bo) * tanhf(c2);
        float z = fc1s[j];
#pragma unroll
        for (int k = 0; k < 32; k++) {
            float v1 = __shfl(hn1, k, 32);
            float v2 = __shfl(hn2, k, 32);
            z += F1s[k * 32 + j] * v1 + F1s[(k + 32) * 32 + j] * v2;
        }
        z = fmaxf(z, 0.f);
        float p = z * fw2s[j];
#pragma unroll
        for (int off = 16; off; off >>= 1) p += __shfl_xor(p, off, 32);
        if (j == 0) out[n] = p + fb2v;
    }
}

// ---- NaN canary: writes a stage code to out[0] only if NaN detected --------
__global__ void k_canary(const float* __restrict__ scale1, const float* __restrict__ H,
                         const float* __restrict__ B, const float* __restrict__ fc1c,
                         float* __restrict__ out) {
    if (threadIdx.x == 0 && blockIdx.x == 0) {
        float code = 0.f;
        if (!(scale1[0] == scale1[0])) code = 301.f;
        if (!(H[5] == H[5]))           code = 302.f;
        if (!(B[5] == B[5]))           code = 303.f;
        if (!(fc1c[0] == fc1c[0]))     code = 304.f;
        if (code != 0.f) out[0] = code;
    }
}

extern "C" void kernel_launch(void* const* d_in, const int* in_sizes, int n_in,
                              void* d_out, int out_size, void* d_ws, size_t ws_size,
                              hipStream_t stream) {
    const float* x    = (const float*)d_in[0];
    const int*   ei   = (const int*)d_in[1];
    const float* ew   = (const float*)d_in[2];
    const float* w1   = (const float*)d_in[3];
    const float* b1   = (const float*)d_in[4];
    const float* g1   = (const float*)d_in[5];
    const float* be1  = (const float*)d_in[6];
    const float* w2   = (const float*)d_in[7];
    const float* b2   = (const float*)d_in[8];
    const float* g2   = (const float*)d_in[9];
    const float* be2  = (const float*)d_in[10];
    const float* wih1 = (const float*)d_in[11];
    const float* bih1 = (const float*)d_in[13];
    const float* bhh1 = (const float*)d_in[14];
    const float* wih2 = (const float*)d_in[15];
    const float* bih2 = (const float*)d_in[17];
    const float* bhh2 = (const float*)d_in[18];
    const float* fw1  = (const float*)d_in[19];
    const float* fb1  = (const float*)d_in[20];
    const float* fw2  = (const float*)d_in[21];
    const float* fb2  = (const float*)d_in[22];
    float* out = (float*)d_out;

    // ---- workspace layout (fp32, ~39.2 MB) ---------------------------------
    char* ws = (char*)d_ws;
    float* stats = (float*)ws;                         // 576 floats @ 0
    float* xsum   = stats + 0;
    float* bn1sum = stats + 32;
    float* bn1sq  = stats + 64;
    float* bn2sum = stats + 96;
    float* bn2sq  = stats + 128;
    float* scale1 = stats + 160;
    float* shift1 = stats + 192;
    float* scale2 = stats + 224;
    float* shift2 = stats + 256;
    float* fc1c   = stats + 288;
    float* lb1    = stats + 320;
    float* lb2    = stats + 448;
    float* deg = (float*)(ws + 4096);                  // 400 KB
    float* A   = (float*)(ws + (512l << 10));          // 12.8 MB @ 0.5 MB
    float* H   = (float*)(ws + 14155776l);             // 12.8 MB @ 13.5 MB
    float* B   = (float*)(ws + 28311552l);             // 12.8 MB @ 27 MB, ends 41.1 MB

    if (ws_size < 41111552ull) {                       // diagnostic: ws too small
        k_marker<<<(N_NODES + 255) / 256, 256, 0, stream>>>(out, N_NODES, 911.f);
        return;
    }

    const int NF = N_NODES * 32;

    k_zero_f<<<1, 256, 0, stream>>>(stats, 160);
    k_zero_f<<<(N_NODES + 255) / 256, 256, 0, stream>>>(deg, N_NODES);
    k_zero_f<<<NF / 256, 256, 0, stream>>>(B, NF);

    k_deg<<<(N_EDGES + 255) / 256, 256, 0, stream>>>(ei, ew, deg);
    k_xmean<<<400, 256, 0, stream>>>(x, xsum);
    k_xw1<<<NF / 256, 256, 0, stream>>>(x, w1, A);
    k_agg<<<(int)((long)N_EDGES * 32 / 256), 256, 0, stream>>>(ei, ew, deg, A, B);
    k_post<<<1024, 256, 0, stream>>>(A, deg, b1, B, bn1sum, bn1sq);
    k_fin1<<<1, 64, 0, stream>>>(bn1sum, bn1sq, g1, be1, scale1, shift1);
    k_aff_xw<<<NF / 256, 256, 0, stream>>>(B, scale1, shift1, w2, H, A);
    k_zero_f<<<NF / 256, 256, 0, stream>>>(B, NF);
    k_agg<<<(int)((long)N_EDGES * 32 / 256), 256, 0, stream>>>(ei, ew, deg, A, B);
    k_post<<<1024, 256, 0, stream>>>(A, deg, b2, B, bn2sum, bn2sq);
    k_fin2<<<1, 128, 0, stream>>>(bn2sum, bn2sq, g2, be2, xsum, fw1, fb1,
                                  bih1, bhh1, bih2, bhh2,
                                  scale2, shift2, fc1c, lb1, lb2);
    k_final<<<1280, 256, 0, stream>>>(H, B, scale2, shift2, wih1, wih2, fw1, fw2,
                                      fb2, fc1c, lb1, lb2, out);
    k_canary<<<1, 64, 0, stream>>>(scale1, H, B, fc1c, out);
}

// Round 4
// 774.399 us; speedup vs baseline: 1.0955x; 1.0955x over previous
//
#include <hip/hip_runtime.h>
#include <hip/hip_bf16.h>

#define N_NODES 100000
#define N_EDGES 1600000
#define BN_EPS 1e-5f

__device__ __forceinline__ float frcp(float x) { return __builtin_amdgcn_rcpf(x); }
__device__ __forceinline__ float fsig(float x) { return frcp(1.0f + __expf(-x)); }
__device__ __forceinline__ float ftanh(float x) {
    // 1 - 2/(exp(2x)+1); exact at +-inf, ~1e-6 rel err
    return 1.0f - 2.0f * frcp(__expf(2.0f * x) + 1.0f);
}

// ---- utility fills ---------------------------------------------------------
__global__ void k_zero_f(float* __restrict__ p, int n) {
    int i = blockIdx.x * 256 + threadIdx.x;
    if (i < n) p[i] = 0.f;
}
__global__ void k_marker(float* __restrict__ p, int n, float v) {
    int i = blockIdx.x * 256 + threadIdx.x;
    if (i < n) p[i] = v;
}

// ---- deg[dst] += ew --------------------------------------------------------
__global__ void k_deg(const int* __restrict__ ei, const float* __restrict__ ew,
                      float* __restrict__ deg) {
    int e = blockIdx.x * 256 + threadIdx.x;
    if (e < N_EDGES) atomicAdd(&deg[ei[N_EDGES + e]], ew[e]);
}

// ---- column sums of x (for skip_avg) ---------------------------------------
__global__ void k_xmean(const float* __restrict__ x, float* __restrict__ xsum) {
    __shared__ float s[256];
    int f = threadIdx.x & 31, rg = threadIdx.x >> 5;
    float acc = 0.f;
    for (int n = blockIdx.x * 8 + rg; n < N_NODES; n += gridDim.x * 8)
        acc += x[n * 32 + f];
    s[threadIdx.x] = acc; __syncthreads();
    for (int st = 128; st >= 32; st >>= 1) {
        if (threadIdx.x < st) s[threadIdx.x] += s[threadIdx.x + st];
        __syncthreads();
    }
    if (threadIdx.x < 32) atomicAdd(&xsum[threadIdx.x], s[threadIdx.x]);
}

// ---- A = x @ W1 ------------------------------------------------------------
__global__ void k_xw1(const float* __restrict__ x, const float* __restrict__ w,
                      float* __restrict__ A) {
    __shared__ float Ws[32 * 33];
    __shared__ float xs[256];
    for (int i = threadIdx.x; i < 1024; i += 256)
        Ws[(i >> 5) * 33 + (i & 31)] = w[i];
    long base = (long)blockIdx.x * 256;
    xs[threadIdx.x] = x[base + threadIdx.x];
    __syncthreads();
    int r = threadIdx.x >> 5, h = threadIdx.x & 31;
    float acc = 0.f;
#pragma unroll
    for (int f = 0; f < 32; f++) acc += xs[r * 32 + f] * Ws[f * 33 + h];
    A[base + threadIdx.x] = acc;
}

// ---- B[dst] += A[src] * norm  (32 lanes per edge, norm inline) -------------
__global__ void k_agg(const int* __restrict__ ei, const float* __restrict__ ew,
                      const float* __restrict__ deg, const float* __restrict__ A,
                      float* __restrict__ B) {
    long gid = (long)blockIdx.x * 256 + threadIdx.x;
    long e = gid >> 5; int f = (int)(gid & 31);
    if (e < N_EDGES) {
        int s = ei[e], d = ei[N_EDGES + e];
        float nm = ew[e] * rsqrtf((deg[s] + 1.0f) * (deg[d] + 1.0f));
        atomicAdd(&B[(long)d * 32 + f], A[(long)s * 32 + f] * nm);
    }
}

// ---- r = relu(B + A/deg + bias) in-place; accumulate BN sum/sumsq ----------
__global__ void k_post(const float* __restrict__ A, const float* __restrict__ deg,
                       const float* __restrict__ bias, float* __restrict__ B,
                       float* __restrict__ sum, float* __restrict__ sq) {
    __shared__ float s1[256], s2[256];
    int f = threadIdx.x & 31, rg = threadIdx.x >> 5;
    float bv = bias[f];
    float a1 = 0.f, a2 = 0.f;
    for (int n = blockIdx.x * 8 + rg; n < N_NODES; n += gridDim.x * 8) {
        long i = (long)n * 32 + f;
        float v = B[i] + A[i] / (deg[n] + 1.0f) + bv;
        v = fmaxf(v, 0.f);
        B[i] = v;
        a1 += v; a2 += v * v;
    }
    s1[threadIdx.x] = a1; s2[threadIdx.x] = a2; __syncthreads();
    for (int st = 128; st >= 32; st >>= 1) {
        if (threadIdx.x < st) {
            s1[threadIdx.x] += s1[threadIdx.x + st];
            s2[threadIdx.x] += s2[threadIdx.x + st];
        }
        __syncthreads();
    }
    if (threadIdx.x < 32) { atomicAdd(&sum[f], s1[f]); atomicAdd(&sq[f], s2[f]); }
}

// ---- BN1 finalize ----------------------------------------------------------
__global__ void k_fin1(const float* __restrict__ sum, const float* __restrict__ sq,
                       const float* __restrict__ g, const float* __restrict__ be,
                       float* __restrict__ scale, float* __restrict__ shift) {
    int t = threadIdx.x;
    if (t < 32) {
        float mu = sum[t] / (float)N_NODES;
        float var = sq[t] / (float)N_NODES - mu * mu;
        float rs = rsqrtf(var + BN_EPS) * g[t];
        scale[t] = rs;
        shift[t] = be[t] - mu * rs;
    }
}

// ---- H = affine(B); A = H @ W2 ---------------------------------------------
__global__ void k_aff_xw(const float* __restrict__ B, const float* __restrict__ scale,
                         const float* __restrict__ shift, const float* __restrict__ w,
                         float* __restrict__ H, float* __restrict__ A) {
    __shared__ float Ws[32 * 33];
    __shared__ float hs[256];
    for (int i = threadIdx.x; i < 1024; i += 256)
        Ws[(i >> 5) * 33 + (i & 31)] = w[i];
    long base = (long)blockIdx.x * 256;
    int f = threadIdx.x & 31;
    float h = B[base + threadIdx.x] * scale[f] + shift[f];
    H[base + threadIdx.x] = h;
    hs[threadIdx.x] = h;
    __syncthreads();
    int r = threadIdx.x >> 5, hc = threadIdx.x & 31;
    float acc = 0.f;
#pragma unroll
    for (int k = 0; k < 32; k++) acc += hs[r * 32 + k] * Ws[k * 33 + hc];
    A[base + threadIdx.x] = acc;
}

// ---- BN2 finalize + fc1 const + combined LSTM biases -----------------------
__global__ void k_fin2(const float* __restrict__ sum, const float* __restrict__ sq,
                       const float* __restrict__ g, const float* __restrict__ be,
                       const float* __restrict__ xsum, const float* __restrict__ fw1,
                       const float* __restrict__ fb1,
                       const float* __restrict__ bih1, const float* __restrict__ bhh1,
                       const float* __restrict__ bih2, const float* __restrict__ bhh2,
                       float* __restrict__ scale, float* __restrict__ shift,
                       float* __restrict__ fc1c, float* __restrict__ lb1,
                       float* __restrict__ lb2) {
    int t = threadIdx.x;
    if (t < 32) {
        float mu = sum[t] / (float)N_NODES;
        float var = sq[t] / (float)N_NODES - mu * mu;
        float rs = rsqrtf(var + BN_EPS) * g[t];
        scale[t] = rs;
        shift[t] = be[t] - mu * rs;
        float c = fb1[t];
        for (int f = 0; f < 32; f++)
            c += (xsum[f] / (float)N_NODES) * fw1[t * 96 + 64 + f];
        fc1c[t] = c;
    }
    if (t < 128) {
        lb1[t] = bih1[t] + bhh1[t];
        lb2[t] = bih2[t] + bhh2[t];
    }
}

// ---- per-node LSTM1 -> LSTM2 -> fc1 -> fc2: ONE THREAD PER NODE ------------
// All weight addresses are wave-uniform (kernel-arg base + constant offset)
// -> compiler emits s_load + v_fma with SGPR operand. Zero LDS, zero shfl.
// PyTorch gate order i,f,g,o; f-gate dead (c0=0 => c = sig(i)*tanh(g)).
__global__ __launch_bounds__(256) void k_final(
    const float* __restrict__ H, const float* __restrict__ B,
    const float* __restrict__ scale2, const float* __restrict__ shift2,
    const float* __restrict__ wih1, const float* __restrict__ wih2,
    const float* __restrict__ fw1, const float* __restrict__ fw2,
    const float* __restrict__ fb2,
    const float* __restrict__ fc1c, const float* __restrict__ lb1,
    const float* __restrict__ lb2, float* __restrict__ out) {
    int n = blockIdx.x * 256 + threadIdx.x;
    if (n >= N_NODES) return;
    float cat[64];
    const float4* Hv = (const float4*)(H + (long)n * 32);
    const float4* Bv = (const float4*)(B + (long)n * 32);
#pragma unroll
    for (int q = 0; q < 8; q++) {
        float4 hv = Hv[q];
        float4 bv = Bv[q];
        cat[q * 4 + 0] = hv.x; cat[q * 4 + 1] = hv.y;
        cat[q * 4 + 2] = hv.z; cat[q * 4 + 3] = hv.w;
        cat[32 + q * 4 + 0] = bv.x * scale2[q * 4 + 0] + shift2[q * 4 + 0];
        cat[32 + q * 4 + 1] = bv.y * scale2[q * 4 + 1] + shift2[q * 4 + 1];
        cat[32 + q * 4 + 2] = bv.z * scale2[q * 4 + 2] + shift2[q * 4 + 2];
        cat[32 + q * 4 + 3] = bv.w * scale2[q * 4 + 3] + shift2[q * 4 + 3];
    }
    float hn1[32];
#pragma unroll
    for (int c = 0; c < 32; c++) {
        float ai = lb1[c], ag = lb1[64 + c], ao = lb1[96 + c];
        const float* wi = wih1 + c * 64;           // i-gate row c
        const float* wg = wih1 + (64 + c) * 64;    // g-gate row c
        const float* wo = wih1 + (96 + c) * 64;    // o-gate row c
#pragma unroll
        for (int k = 0; k < 64; k++) {
            float v = cat[k];
            ai += v * wi[k]; ag += v * wg[k]; ao += v * wo[k];
        }
        float c1 = fsig(ai) * ftanh(ag);
        hn1[c] = fsig(ao) * ftanh(c1);
    }
    float hn2[32];
#pragma unroll
    for (int c = 0; c < 32; c++) {
        float bi = lb2[c], bg = lb2[64 + c], bo = lb2[96 + c];
        const float* wi = wih2 + c * 32;
        const float* wg = wih2 + (64 + c) * 32;
        const float* wo = wih2 + (96 + c) * 32;
#pragma unroll
        for (int k = 0; k < 32; k++) {
            float v = hn1[k];
            bi += v * wi[k]; bg += v * wg[k]; bo += v * wo[k];
        }
        float c2 = fsig(bi) * ftanh(bg);
        hn2[c] = fsig(bo) * ftanh(c2);
    }
    float acc = fb2[0];
#pragma unroll
    for (int j = 0; j < 32; j++) {
        float z = fc1c[j];                          // fb1 + skip_avg part
        const float* r = fw1 + j * 96;
#pragma unroll
        for (int k = 0; k < 32; k++)
            z += hn1[k] * r[k] + hn2[k] * r[32 + k];
        acc += fmaxf(z, 0.f) * fw2[j];
    }
    out[n] = acc;
}

extern "C" void kernel_launch(void* const* d_in, const int* in_sizes, int n_in,
                              void* d_out, int out_size, void* d_ws, size_t ws_size,
                              hipStream_t stream) {
    const float* x    = (const float*)d_in[0];
    const int*   ei   = (const int*)d_in[1];
    const float* ew   = (const float*)d_in[2];
    const float* w1   = (const float*)d_in[3];
    const float* b1   = (const float*)d_in[4];
    const float* g1   = (const float*)d_in[5];
    const float* be1  = (const float*)d_in[6];
    const float* w2   = (const float*)d_in[7];
    const float* b2   = (const float*)d_in[8];
    const float* g2   = (const float*)d_in[9];
    const float* be2  = (const float*)d_in[10];
    const float* wih1 = (const float*)d_in[11];
    const float* bih1 = (const float*)d_in[13];
    const float* bhh1 = (const float*)d_in[14];
    const float* wih2 = (const float*)d_in[15];
    const float* bih2 = (const float*)d_in[17];
    const float* bhh2 = (const float*)d_in[18];
    const float* fw1  = (const float*)d_in[19];
    const float* fb1  = (const float*)d_in[20];
    const float* fw2  = (const float*)d_in[21];
    const float* fb2  = (const float*)d_in[22];
    float* out = (float*)d_out;

    // ---- workspace layout (fp32, ~41.1 MB) ---------------------------------
    char* ws = (char*)d_ws;
    float* stats = (float*)ws;                         // 576 floats @ 0
    float* xsum   = stats + 0;
    float* bn1sum = stats + 32;
    float* bn1sq  = stats + 64;
    float* bn2sum = stats + 96;
    float* bn2sq  = stats + 128;
    float* scale1 = stats + 160;
    float* shift1 = stats + 192;
    float* scale2 = stats + 224;
    float* shift2 = stats + 256;
    float* fc1c   = stats + 288;
    float* lb1    = stats + 320;
    float* lb2    = stats + 448;
    float* deg = (float*)(ws + 4096);                  // 400 KB
    float* A   = (float*)(ws + (512l << 10));          // 12.8 MB @ 0.5 MB
    float* H   = (float*)(ws + 14155776l);             // 12.8 MB @ 13.5 MB
    float* B   = (float*)(ws + 28311552l);             // 12.8 MB @ 27 MB, ends 41.1 MB

    if (ws_size < 41111552ull) {                       // diagnostic: ws too small
        k_marker<<<(N_NODES + 255) / 256, 256, 0, stream>>>(out, N_NODES, 911.f);
        return;
    }

    const int NF = N_NODES * 32;

    k_zero_f<<<1, 256, 0, stream>>>(stats, 160);
    k_zero_f<<<(N_NODES + 255) / 256, 256, 0, stream>>>(deg, N_NODES);
    k_zero_f<<<NF / 256, 256, 0, stream>>>(B, NF);

    k_deg<<<(N_EDGES + 255) / 256, 256, 0, stream>>>(ei, ew, deg);
    k_xmean<<<400, 256, 0, stream>>>(x, xsum);
    k_xw1<<<NF / 256, 256, 0, stream>>>(x, w1, A);
    k_agg<<<(int)((long)N_EDGES * 32 / 256), 256, 0, stream>>>(ei, ew, deg, A, B);
    k_post<<<1024, 256, 0, stream>>>(A, deg, b1, B, bn1sum, bn1sq);
    k_fin1<<<1, 64, 0, stream>>>(bn1sum, bn1sq, g1, be1, scale1, shift1);
    k_aff_xw<<<NF / 256, 256, 0, stream>>>(B, scale1, shift1, w2, H, A);
    k_zero_f<<<NF / 256, 256, 0, stream>>>(B, NF);
    k_agg<<<(int)((long)N_EDGES * 32 / 256), 256, 0, stream>>>(ei, ew, deg, A, B);
    k_post<<<1024, 256, 0, stream>>>(A, deg, b2, B, bn2sum, bn2sq);
    k_fin2<<<1, 128, 0, stream>>>(bn2sum, bn2sq, g2, be2, xsum, fw1, fb1,
                                  bih1, bhh1, bih2, bhh2,
                                  scale2, shift2, fc1c, lb1, lb2);
    k_final<<<(N_NODES + 255) / 256, 256, 0, stream>>>(
        H, B, scale2, shift2, wih1, wih2, fw1, fw2,
        fb2, fc1c, lb1, lb2, out);
}